// Round 1
// baseline (418.460 us; speedup 1.0000x reference)
//
#include <hip/hip_runtime.h>

#define EPS_F 1e-5f

__device__ __forceinline__ float wave_sum64(float v) {
  #pragma unroll
  for (int off = 32; off; off >>= 1) v += __shfl_xor(v, off);
  return v;
}

__global__ __launch_bounds__(256) void nerf_volrend(
    const float* __restrict__ rays,
    const float* __restrict__ sigc,
    const float* __restrict__ rgbc,
    const float* __restrict__ sigf,
    const float* __restrict__ rgbf,
    float* __restrict__ out, int n_rays)
{
  const int wave = threadIdx.x >> 6;
  const int lane = threadIdx.x & 63;
  const int ray  = (blockIdx.x << 2) + wave;

  __shared__ float s_cdf [4][64];
  __shared__ float s_bins[4][64];
  __shared__ float s_zc  [4][64];
  __shared__ float s_zf  [4][64];
  __shared__ float s_zcb [4][128];

  const float nearv = rays[ray*8 + 6];
  const float farv  = rays[ray*8 + 7];

  // ---------------- coarse composite ----------------
  const float t = (float)lane * 0.015625f;            // lane/64, exact fp32
  const float z = nearv * (1.0f - t) + farv * t;
  const float znext = __shfl_down(z, 1);
  const float delta = (lane == 63) ? 1e10f : (znext - z);
  float sgv = sigc[ray*64 + lane];
  sgv = fmaxf(sgv, 0.0f);
  const float a = 1.0f - __expf(-delta * sgv);
  const float sh = 1.0f - a + 1e-10f;

  // inclusive prefix product of sh across the wave
  float pin = sh;
  #pragma unroll
  for (int off = 1; off < 64; off <<= 1) {
    float tmp = __shfl_up(pin, off);
    if (lane >= off) pin *= tmp;
  }
  float T = __shfl_up(pin, 1);
  if (lane == 0) T = 1.0f;
  const float w = a * T;

  const float r0 = rgbc[ray*192 + lane*3 + 0];
  const float r1 = rgbc[ray*192 + lane*3 + 1];
  const float r2 = rgbc[ray*192 + lane*3 + 2];

  const float wsum = wave_sum64(w);
  const float cR = wave_sum64(w * r0);
  const float cG = wave_sum64(w * r1);
  const float cB = wave_sum64(w * r2);
  const float cD = wave_sum64(w * z);

  if (lane == 0) {
    out[ray*3 + 0]      = cR + 1.0f - wsum;
    out[ray*3 + 1]      = cG + 1.0f - wsum;
    out[ray*3 + 2]      = cB + 1.0f - wsum;
    out[n_rays*3 + ray] = wsum;
    out[n_rays*4 + ray] = cD + (1.0f - wsum) * farv;
  }

  // ---------------- sample_fine (inverse-CDF) ----------------
  const float wnext = __shfl_down(w, 1);              // weights[lane+1]
  const float wp = (lane < 62) ? (wnext + EPS_F) : 0.0f;
  const float wpsum = wave_sum64(wp);
  const float pdf = wp / wpsum;
  float csum = pdf;                                   // inclusive prefix sum
  #pragma unroll
  for (int off = 1; off < 64; off <<= 1) {
    float tmp = __shfl_up(csum, off);
    if (lane >= off) csum += tmp;
  }

  s_zc[wave][lane] = z;
  if (lane < 63) s_bins[wave][lane] = 0.5f * (z + znext);
  if (lane < 62) s_cdf[wave][lane + 1] = csum;
  if (lane == 0) s_cdf[wave][0] = 0.0f;
  __syncthreads();

  const float* cdf  = s_cdf[wave];
  const float* bins = s_bins[wave];
  const float u = (lane == 63) ? 1.0f : (float)lane * (1.0f / 63.0f);
  // searchsorted(cdf[0..62], u, side='right') == count(cdf <= u), branchless
  int pos = 0;
  #pragma unroll
  for (int stp = 32; stp; stp >>= 1) {
    int np = pos + stp;
    if (np <= 63 && cdf[np - 1] <= u) pos = np;
  }
  const int below = max(pos - 1, 0);
  const int above = min(pos, 62);
  const float cdf_b = cdf[below], cdf_a = cdf[above];
  const float bin_b = bins[below], bin_a = bins[above];
  float dn = cdf_a - cdf_b;
  if (dn < EPS_F) dn = 1.0f;
  const float zf = bin_b + (u - cdf_b) / dn * (bin_a - bin_b);
  s_zf[wave][lane] = zf;
  __syncthreads();

  // ---------------- stable merge of z_coarse & z_fine ----------------
  const float* zcl = s_zc[wave];
  const float* zfl = s_zf[wave];
  int cf = 0;   // count of zf <  z   (coarse element rank contribution)
  #pragma unroll
  for (int stp = 64; stp; stp >>= 1) {
    int np = cf + stp;
    if (np <= 64 && zfl[np - 1] < z) cf = np;
  }
  int cc = 0;   // count of zc <= zf  (fine element rank contribution)
  #pragma unroll
  for (int stp = 64; stp; stp >>= 1) {
    int np = cc + stp;
    if (np <= 64 && zcl[np - 1] <= zf) cc = np;
  }
  s_zcb[wave][lane + cf] = z;
  s_zcb[wave][lane + cc] = zf;
  __syncthreads();

  // ---------------- fine composite (2 samples / lane) ----------------
  const float* zcb = s_zcb[wave];
  const float z0 = zcb[2*lane];
  const float z1 = zcb[2*lane + 1];
  const int   i2 = (lane == 63) ? 0 : (2*lane + 2);
  const float z2 = zcb[i2];
  const float d0 = z1 - z0;
  const float d1 = (lane == 63) ? 1e10f : (z2 - z1);

  const float2 sgf = ((const float2*)(sigf + (size_t)ray*128))[lane];
  const float s0 = fmaxf(sgf.x, 0.0f);
  const float s1 = fmaxf(sgf.y, 0.0f);
  const float a0 = 1.0f - __expf(-d0 * s0);
  const float a1 = 1.0f - __expf(-d1 * s1);
  const float t0 = 1.0f - a0 + 1e-10f;
  const float t1 = 1.0f - a1 + 1e-10f;

  float pp = t0 * t1;                                  // pair product scan
  #pragma unroll
  for (int off = 1; off < 64; off <<= 1) {
    float tmp = __shfl_up(pp, off);
    if (lane >= off) pp *= tmp;
  }
  float Pex = __shfl_up(pp, 1);
  if (lane == 0) Pex = 1.0f;
  const float w0 = a0 * Pex;
  const float w1 = a1 * Pex * t0;

  const float* rb = rgbf + (size_t)ray*384 + lane*6;
  const float2 rA = *(const float2*)(rb + 0);
  const float2 rB = *(const float2*)(rb + 2);
  const float2 rC = *(const float2*)(rb + 4);
  // sample0 rgb = (rA.x, rA.y, rB.x); sample1 rgb = (rB.y, rC.x, rC.y)

  const float fR = wave_sum64(w0 * rA.x + w1 * rB.y);
  const float fG = wave_sum64(w0 * rA.y + w1 * rC.x);
  const float fB = wave_sum64(w0 * rB.x + w1 * rC.y);
  const float fD = wave_sum64(w0 * z0   + w1 * z1);
  const float fW = wave_sum64(w0 + w1);

  if (lane == 0) {
    out[n_rays*5 + ray*3 + 0] = fR + 1.0f - fW;
    out[n_rays*5 + ray*3 + 1] = fG + 1.0f - fW;
    out[n_rays*5 + ray*3 + 2] = fB + 1.0f - fW;
    out[n_rays*8 + ray]       = fW;
    out[n_rays*9 + ray]       = fD + (1.0f - fW) * farv;
  }
}

extern "C" void kernel_launch(void* const* d_in, const int* in_sizes, int n_in,
                              void* d_out, int out_size, void* d_ws, size_t ws_size,
                              hipStream_t stream) {
  const float* rays = (const float*)d_in[0];
  const float* sigc = (const float*)d_in[1];
  const float* rgbc = (const float*)d_in[2];
  const float* sigf = (const float*)d_in[3];
  const float* rgbf = (const float*)d_in[4];
  float* out = (float*)d_out;
  const int n_rays = in_sizes[0] / 8;       // 131072
  const int blocks = n_rays / 4;            // 4 rays (waves) per 256-thread block
  nerf_volrend<<<blocks, 256, 0, stream>>>(rays, sigc, rgbc, sigf, rgbf, out, n_rays);
}

// Round 2
// 399.520 us; speedup vs baseline: 1.0474x; 1.0474x over previous
//
#include <hip/hip_runtime.h>

#define EPS_F 1e-5f

// DPP move with explicit 'old' (identity) for masked/invalid lanes.
#define DPPF(old, x, ctrl, rm, bm) \
  __int_as_float(__builtin_amdgcn_update_dpp(__float_as_int(old), __float_as_int(x), ctrl, rm, bm, false))

// Canonical gfx9 wave64 inclusive scans: row_shr 1,2,4,8 then
// row_bcast15 (rows 1,3) and row_bcast31 (rows 2,3). VALU pipe, no LDS.
__device__ __forceinline__ float scan_add64(float x) {
  x += DPPF(0.0f, x, 0x111, 0xf, 0xf);
  x += DPPF(0.0f, x, 0x112, 0xf, 0xf);
  x += DPPF(0.0f, x, 0x114, 0xf, 0xf);
  x += DPPF(0.0f, x, 0x118, 0xf, 0xf);
  x += DPPF(0.0f, x, 0x142, 0xa, 0xf);
  x += DPPF(0.0f, x, 0x143, 0xc, 0xf);
  return x;
}
__device__ __forceinline__ float scan_mul64(float x) {
  x *= DPPF(1.0f, x, 0x111, 0xf, 0xf);
  x *= DPPF(1.0f, x, 0x112, 0xf, 0xf);
  x *= DPPF(1.0f, x, 0x114, 0xf, 0xf);
  x *= DPPF(1.0f, x, 0x118, 0xf, 0xf);
  x *= DPPF(1.0f, x, 0x142, 0xa, 0xf);
  x *= DPPF(1.0f, x, 0x143, 0xc, 0xf);
  return x;
}
__device__ __forceinline__ float wave_total(float x) {
  float s = scan_add64(x);
  return __int_as_float(__builtin_amdgcn_readlane(__float_as_int(s), 63));
}

__global__ __launch_bounds__(256) void nerf_volrend(
    const float* __restrict__ rays,
    const float* __restrict__ sigc,
    const float* __restrict__ rgbc,
    const float* __restrict__ sigf,
    const float* __restrict__ rgbf,
    float* __restrict__ out, int n_rays)
{
  const int wave = threadIdx.x >> 6;
  const int lane = threadIdx.x & 63;
  const int ray  = (blockIdx.x << 2) + wave;

  // Wave-private LDS slices: no __syncthreads needed anywhere.
  __shared__ float s_cdf[4][64];   // 63 used
  __shared__ int   s_cc [4][64];   // fine-sample coarse-ranks (sorted)
  __shared__ float s_zcb[4][128];  // merged z

  const float nearv = rays[ray*8 + 6];
  const float farv  = rays[ray*8 + 7];

  // ---------------- coarse composite ----------------
  const float t  = (float)lane * 0.015625f;
  const float tn = (float)(lane + 1) * 0.015625f;
  const float z     = nearv * (1.0f - t)  + farv * t;
  const float znext = nearv * (1.0f - tn) + farv * tn;   // == ref z[lane+1]
  const float delta = (lane == 63) ? 1e10f : (znext - z);
  float sgv = sigc[ray*64 + lane];
  sgv = fmaxf(sgv, 0.0f);
  const float a  = 1.0f - __expf(-delta * sgv);
  const float sh = 1.0f - a + 1e-10f;

  const float pin = scan_mul64(sh);          // inclusive prefix product
  float T = __shfl_up(pin, 1);               // exclusive (1 ds_bpermute)
  if (lane == 0) T = 1.0f;
  const float w = a * T;

  const float r0 = rgbc[ray*192 + lane*3 + 0];
  const float r1 = rgbc[ray*192 + lane*3 + 1];
  const float r2 = rgbc[ray*192 + lane*3 + 2];

  const float wsum = wave_total(w);
  const float cR = wave_total(w * r0);
  const float cG = wave_total(w * r1);
  const float cB = wave_total(w * r2);
  const float cD = wave_total(w * z);

  if (lane == 0) {
    out[ray*3 + 0]      = cR + 1.0f - wsum;
    out[ray*3 + 1]      = cG + 1.0f - wsum;
    out[ray*3 + 2]      = cB + 1.0f - wsum;
    out[n_rays*3 + ray] = wsum;
    out[n_rays*4 + ray] = cD + (1.0f - wsum) * farv;
  }

  // ---------------- sample_fine (inverse-CDF) ----------------
  const float wnext = __shfl_down(w, 1);               // weights[lane+1]
  const float wp    = (lane < 62) ? (wnext + EPS_F) : 0.0f;
  const float wpsum = wave_total(wp);
  const float csum  = scan_add64(wp / wpsum);          // inclusive cdf

  if (lane < 62) s_cdf[wave][lane + 1] = csum;
  if (lane == 0) s_cdf[wave][0] = 0.0f;

  const float* cdf = s_cdf[wave];
  const float u = (lane == 63) ? 1.0f : (float)lane * (1.0f / 63.0f);
  // searchsorted(cdf[0..62], u, side='right') == count(cdf <= u)
  int pos = 0;
  #pragma unroll
  for (int stp = 32; stp; stp >>= 1) {
    int np = pos + stp;
    if (np <= 63 && cdf[np - 1] <= u) pos = np;
  }
  const int below = max(pos - 1, 0);
  const int above = min(pos, 62);
  const float cdf_b = cdf[below], cdf_a = cdf[above];
  // bins arithmetic (uniform z grid): bin(k) = 0.5*(z(k)+z(k+1))
  const float tb  = (float)below * 0.015625f, tb1 = (float)(below + 1) * 0.015625f;
  const float ta  = (float)above * 0.015625f, ta1 = (float)(above + 1) * 0.015625f;
  const float bin_b = 0.5f * ((nearv*(1.0f-tb)  + farv*tb)  + (nearv*(1.0f-tb1) + farv*tb1));
  const float bin_a = 0.5f * ((nearv*(1.0f-ta)  + farv*ta)  + (nearv*(1.0f-ta1) + farv*ta1));
  float dn = cdf_a - cdf_b;
  if (dn < EPS_F) dn = 1.0f;
  const float zf = bin_b + (u - cdf_b) / dn * (bin_a - bin_b);

  // ---------------- merge via ranks (uniform coarse grid) ----------------
  // cc_j = #{k: z_coarse(k) <= zf_j}  -- arithmetic, since grid is uniform
  const float inv_step = 64.0f / (farv - nearv);
  int cc = (int)floorf((zf - nearv) * inv_step) + 1;
  cc = min(max(cc, 0), 64);
  s_cc[wave][lane] = cc;                       // sorted (zf sorted)
  s_zcb[wave][lane + cc] = zf;                 // fine scatter

  // cf_i = #{j: cc_j <= i}  == #{j: zf_j < z_i}  (rank of coarse sample i)
  const int* ccl = s_cc[wave];
  int cf = 0;
  #pragma unroll
  for (int stp = 64; stp; stp >>= 1) {
    int np = cf + stp;
    if (np <= 64 && ccl[np - 1] <= lane) cf = np;
  }
  s_zcb[wave][lane + cf] = z;                  // coarse scatter

  // ---------------- fine composite (2 samples / lane) ----------------
  const float* zcb = s_zcb[wave];
  const float2 zp = ((const float2*)zcb)[lane];        // ds_read_b64
  const float z0 = zp.x, z1 = zp.y;
  const float z2 = zcb[(lane == 63) ? 127 : (2*lane + 2)];
  const float d0 = z1 - z0;
  const float d1 = (lane == 63) ? 1e10f : (z2 - z1);

  const float2 sgf = ((const float2*)(sigf + (size_t)ray*128))[lane];
  const float s0 = fmaxf(sgf.x, 0.0f);
  const float s1 = fmaxf(sgf.y, 0.0f);
  const float a0 = 1.0f - __expf(-d0 * s0);
  const float a1 = 1.0f - __expf(-d1 * s1);
  const float t0 = 1.0f - a0 + 1e-10f;
  const float t1 = 1.0f - a1 + 1e-10f;

  const float pp = scan_mul64(t0 * t1);        // pair-product scan
  float Pex = __shfl_up(pp, 1);
  if (lane == 0) Pex = 1.0f;
  const float w0 = a0 * Pex;
  const float w1 = a1 * Pex * t0;

  const float* rb = rgbf + (size_t)ray*384 + lane*6;
  const float2 rA = *(const float2*)(rb + 0);
  const float2 rB = *(const float2*)(rb + 2);
  const float2 rC = *(const float2*)(rb + 4);

  const float fR = wave_total(w0 * rA.x + w1 * rB.y);
  const float fG = wave_total(w0 * rA.y + w1 * rC.x);
  const float fB = wave_total(w0 * rB.x + w1 * rC.y);
  const float fD = wave_total(w0 * z0   + w1 * z1);
  const float fW = wave_total(w0 + w1);

  if (lane == 0) {
    out[n_rays*5 + ray*3 + 0] = fR + 1.0f - fW;
    out[n_rays*5 + ray*3 + 1] = fG + 1.0f - fW;
    out[n_rays*5 + ray*3 + 2] = fB + 1.0f - fW;
    out[n_rays*8 + ray]       = fW;
    out[n_rays*9 + ray]       = fD + (1.0f - fW) * farv;
  }
}

extern "C" void kernel_launch(void* const* d_in, const int* in_sizes, int n_in,
                              void* d_out, int out_size, void* d_ws, size_t ws_size,
                              hipStream_t stream) {
  const float* rays = (const float*)d_in[0];
  const float* sigc = (const float*)d_in[1];
  const float* rgbc = (const float*)d_in[2];
  const float* sigf = (const float*)d_in[3];
  const float* rgbf = (const float*)d_in[4];
  float* out = (float*)d_out;
  const int n_rays = in_sizes[0] / 8;       // 131072
  const int blocks = n_rays / 4;            // 4 rays (waves) per 256-thread block
  nerf_volrend<<<blocks, 256, 0, stream>>>(rays, sigc, rgbc, sigf, rgbf, out, n_rays);
}